// Round 4
// baseline (2600.266 us; speedup 1.0000x reference)
//
#include <hip/hip_runtime.h>

#define NUM_EMB 2048
#define DIM     128
#define NVEC    65536            // 64*32*32
#define MARGIN  4.0e-3f          // >= 4.6x worst-case approx error (see analysis)
#define CAP     32               // candidate cap per row; overflow -> exact fallback
#define CHUNK   256              // codes per LDS chunk
#define NCHUNK  (NUM_EMB / CHUNK)
#define ES      136              // ushort stride per code row in LDS: 272 B, 16B-aligned, 2-way banks (free)

typedef float  f32x4 __attribute__((ext_vector_type(4)));
typedef short  s16x8 __attribute__((ext_vector_type(8)));

// RNE float -> bf16 (matches __float2bfloat16 rounding; inputs are finite)
__device__ __forceinline__ ushort f2bf(float f) {
    unsigned u = __float_as_uint(f);
    u = (u + 0x7fffu + ((u >> 16) & 1u)) >> 16;
    return (ushort)u;
}

// ---------------------------------------------------------------------------
// Exact replica of numpy pairwise_sum for n=128 fp32 applied to v*v.
// Verified bit-exact vs the np reference (R2/R3 passed absmax 0.0).
// DO NOT REASSOCIATE.
// ---------------------------------------------------------------------------
__device__ __forceinline__ float np_pairwise_sumsq_128(const float* __restrict__ p)
{
    float r[8];
    #pragma unroll
    for (int j = 0; j < 8; ++j) { float v = p[j]; r[j] = __fmul_rn(v, v); }
    #pragma unroll
    for (int i = 8; i < 128; i += 8)
        #pragma unroll
        for (int j = 0; j < 8; ++j) { float v = p[i + j]; r[j] = __fadd_rn(r[j], __fmul_rn(v, v)); }
    float s01 = __fadd_rn(r[0], r[1]);
    float s23 = __fadd_rn(r[2], r[3]);
    float s45 = __fadd_rn(r[4], r[5]);
    float s67 = __fadd_rn(r[6], r[7]);
    return __fadd_rn(__fadd_rn(s01, s23), __fadd_rn(s45, s67));
}

// ---------------------------------------------------------------------------
// Kernel 1: enorm (np-exact), zero loss accum + candidate counters
// ---------------------------------------------------------------------------
__global__ __launch_bounds__(256)
void prep_kernel(const float* __restrict__ emb,
                 float* __restrict__ enorm,
                 float* __restrict__ accum,
                 unsigned* __restrict__ cand_cnt)
{
    int g = blockIdx.x * 256 + threadIdx.x;   // grid = 65536 exactly
    cand_cnt[g] = 0u;
    if (g == 0) *accum = 0.0f;
    if (g < NUM_EMB)
        enorm[g] = np_pairwise_sumsq_128(emb + (size_t)g * DIM);
}

// ---------------------------------------------------------------------------
// Kernel 2: bf16-MFMA approx scores, two passes:
//   pass 0: per-row running min of g = C_j - 2*dot_approx
//   pass 1: capture all codes with g <= min + MARGIN into global cand lists
// Block = 256 thr (4 waves); wave owns 64 rows (4 row-tiles of 16);
// E staged to LDS in 256-code chunks (fp32->bf16 on the fly).
// MFMA 16x16x32 bf16 layouts (HW-verified): A/B frag k=(lane>>4)*8+j,
// m/n=lane&15; D: row=(lane>>4)*4+reg, col=lane&15.
// ---------------------------------------------------------------------------
__global__ __launch_bounds__(256, 1)
void approx_kernel(const float* __restrict__ z,
                   const float* __restrict__ emb,
                   const float* __restrict__ enorm,
                   unsigned* __restrict__ cand_cnt,
                   ushort* __restrict__ cand)
{
    __shared__ __align__(16) ushort eS[CHUNK * ES];   // 69,632 B
    __shared__ float cS[CHUNK];

    const int tid  = threadIdx.x;
    const int w    = tid >> 6;            // wave 0..3
    const int lane = tid & 63;
    const int col  = lane & 15;           // m (A) / n (B) / D col
    const int quad = lane >> 4;           // k-group / D row-group
    const int rowbase = blockIdx.x * 256 + w * 64;

    // A-fragments: 4 row-tiles x 4 k-tiles, loaded once, fp32 -> bf16 RNE
    s16x8 afrag[4][4];
    #pragma unroll
    for (int rt = 0; rt < 4; ++rt) {
        const float* zr = z + (size_t)(rowbase + rt * 16 + col) * DIM;
        #pragma unroll
        for (int kt = 0; kt < 4; ++kt) {
            const float4* p = (const float4*)(zr + kt * 32 + quad * 8);
            float4 f0 = p[0], f1 = p[1];
            s16x8 a;
            a[0] = (short)f2bf(f0.x); a[1] = (short)f2bf(f0.y);
            a[2] = (short)f2bf(f0.z); a[3] = (short)f2bf(f0.w);
            a[4] = (short)f2bf(f1.x); a[5] = (short)f2bf(f1.y);
            a[6] = (short)f2bf(f1.z); a[7] = (short)f2bf(f1.w);
            afrag[rt][kt] = a;
        }
    }

    // pass 0: running min; after butterfly this becomes the capture threshold
    float minv[4][4];
    #pragma unroll
    for (int rt = 0; rt < 4; ++rt)
        #pragma unroll
        for (int r = 0; r < 4; ++r) minv[rt][r] = 3.0e38f;

    for (int pass = 0; pass < 2; ++pass) {
        for (int c = 0; c < NCHUNK; ++c) {
            __syncthreads();              // previous chunk's readers done
            // stage chunk: 256 codes x 128 fp32 -> bf16 LDS (stride ES)
            #pragma unroll
            for (int i = 0; i < 32; ++i) {
                int li = i * 256 + tid;
                int code = li >> 5, fc = li & 31;
                float4 v = ((const float4*)(emb + (size_t)(c * CHUNK + code) * DIM))[fc];
                ushort4 b;
                b.x = f2bf(v.x); b.y = f2bf(v.y); b.z = f2bf(v.z); b.w = f2bf(v.w);
                *(ushort4*)&eS[code * ES + fc * 4] = b;
            }
            if (tid < CHUNK) cS[tid] = enorm[c * CHUNK + tid];
            __syncthreads();

            for (int t = 0; t < 16; ++t) {
                s16x8 bfrag[4];
                #pragma unroll
                for (int kt = 0; kt < 4; ++kt)
                    bfrag[kt] = *(const s16x8*)&eS[(t * 16 + col) * ES + kt * 32 + quad * 8];

                f32x4 acc[4];
                #pragma unroll
                for (int rt = 0; rt < 4; ++rt) {
                    f32x4 a = {0.0f, 0.0f, 0.0f, 0.0f};
                    #pragma unroll
                    for (int kt = 0; kt < 4; ++kt)
                        a = __builtin_amdgcn_mfma_f32_16x16x32_bf16(afrag[rt][kt], bfrag[kt], a, 0, 0, 0);
                    acc[rt] = a;
                }

                float Cc     = cS[t * 16 + col];
                int   code_g = c * CHUNK + t * 16 + col;
                #pragma unroll
                for (int rt = 0; rt < 4; ++rt)
                    #pragma unroll
                    for (int r = 0; r < 4; ++r) {
                        float g = fmaf(-2.0f, acc[rt][r], Cc);
                        if (pass == 0) {
                            minv[rt][r] = fminf(minv[rt][r], g);
                        } else if (g <= minv[rt][r]) {      // minv holds min+MARGIN
                            int row_g = rowbase + rt * 16 + quad * 4 + r;
                            unsigned pos = atomicAdd(&cand_cnt[row_g], 1u);
                            if (pos < CAP) cand[(size_t)row_g * CAP + pos] = (ushort)code_g;
                        }
                    }
            }
        }
        if (pass == 0) {
            // butterfly min across the 16 cols of each quad (rows are per-quad);
            // every lane ends with the row min -> threshold in registers
            #pragma unroll
            for (int rt = 0; rt < 4; ++rt)
                #pragma unroll
                for (int r = 0; r < 4; ++r) {
                    float v = minv[rt][r];
                    v = fminf(v, __shfl_xor(v, 1, 64));
                    v = fminf(v, __shfl_xor(v, 2, 64));
                    v = fminf(v, __shfl_xor(v, 4, 64));
                    v = fminf(v, __shfl_xor(v, 8, 64));
                    minv[rt][r] = v + MARGIN;
                }
        }
    }
}

// ---------------------------------------------------------------------------
// Kernel 3: exact fp32-replica re-rank of candidates (one thread per row).
//   dist = fl(fl(A - 2*dot) + C); dot = sequential ascending-k single-acc
//   fmaf chain (bit-exact vs np/BLAS — verified R2/R3). First-index tie rule
//   via (v,idx) compare. cnt > CAP (≈ never) -> exact full scan.
// ---------------------------------------------------------------------------
__global__ __launch_bounds__(256, 1)
void rerank_kernel(const float* __restrict__ z,
                   const float* __restrict__ emb,
                   const float* __restrict__ enorm,
                   const unsigned* __restrict__ cand_cnt,
                   const ushort* __restrict__ cand,
                   int* __restrict__ out_idx)
{
    const int row = blockIdx.x * 256 + threadIdx.x;

    float zr[DIM];
    const float4* zp = (const float4*)(z + (size_t)row * DIM);
    #pragma unroll
    for (int i = 0; i < 32; ++i) {
        float4 v = zp[i];
        zr[i * 4 + 0] = v.x; zr[i * 4 + 1] = v.y;
        zr[i * 4 + 2] = v.z; zr[i * 4 + 3] = v.w;
    }
    float A = np_pairwise_sumsq_128(zr);

    unsigned cnt = cand_cnt[row];
    float bv = 3.0e38f;
    int   bi = 0x7fffffff;

    if (cnt <= CAP) {
        for (unsigned ci = 0; ci < cnt; ++ci) {
            int j = (int)cand[(size_t)row * CAP + ci];
            const float* er = emb + (size_t)j * DIM;
            float dot = 0.0f;
            #pragma unroll
            for (int k = 0; k < DIM; ++k) dot = fmaf(zr[k], er[k], dot);
            float t1 = fmaf(-2.0f, dot, A);
            float s  = __fadd_rn(t1, enorm[j]);
            if (s < bv || (s == bv && j < bi)) { bv = s; bi = j; }
        }
    } else {
        for (int j = 0; j < NUM_EMB; ++j) {             // exact fallback, ascending
            const float* er = emb + (size_t)j * DIM;
            float dot = 0.0f;
            #pragma unroll
            for (int k = 0; k < DIM; ++k) dot = fmaf(zr[k], er[k], dot);
            float t1 = fmaf(-2.0f, dot, A);
            float s  = __fadd_rn(t1, enorm[j]);
            if (s < bv) { bv = s; bi = j; }
        }
    }
    out_idx[row] = bi;
}

// ---------------------------------------------------------------------------
// Kernel 4: quantized_st = fl(z + fl(q - z)), indices as float, loss partial
// (unchanged — verified R2/R3)
// ---------------------------------------------------------------------------
__global__ __launch_bounds__(256)
void gather_kernel(const float* __restrict__ z,
                   const float* __restrict__ emb,
                   const int* __restrict__ idx,
                   float* __restrict__ out_q,
                   float* __restrict__ out_idx_f,
                   float* __restrict__ accum)
{
    const int tid = threadIdx.x;
    const int gid = blockIdx.x * 256 + tid;
    const int v   = gid >> 5;
    const int c   = gid & 31;

    int j = idx[v];
    float4 q  = ((const float4*)(emb + (size_t)j * DIM))[c];
    float4 zv = ((const float4*)(z   + (size_t)v * DIM))[c];

    float4 o;
    o.x = __fadd_rn(zv.x, __fsub_rn(q.x, zv.x));
    o.y = __fadd_rn(zv.y, __fsub_rn(q.y, zv.y));
    o.z = __fadd_rn(zv.z, __fsub_rn(q.z, zv.z));
    o.w = __fadd_rn(zv.w, __fsub_rn(q.w, zv.w));
    ((float4*)out_q)[(size_t)v * 32 + c] = o;

    float dx = q.x - zv.x, dy = q.y - zv.y, dz = q.z - zv.z, dw = q.w - zv.w;
    float part = dx * dx + dy * dy + dz * dz + dw * dw;

    #pragma unroll
    for (int off = 32; off > 0; off >>= 1)
        part += __shfl_down(part, off, 64);

    __shared__ float wsum[4];
    if ((tid & 63) == 0) wsum[tid >> 6] = part;
    __syncthreads();
    if (tid == 0) atomicAdd(accum, wsum[0] + wsum[1] + wsum[2] + wsum[3]);

    if (tid < 8) {
        int vv = blockIdx.x * 8 + tid;
        out_idx_f[vv] = (float)idx[vv];
    }
}

// ---------------------------------------------------------------------------
// Kernel 5: loss = (1 + beta) * sum / (N*D), beta = 0.25
// ---------------------------------------------------------------------------
__global__ void finalize_kernel(const float* __restrict__ accum,
                                float* __restrict__ out_loss)
{
    *out_loss = 1.25f * (*accum) / 8388608.0f;
}

// ---------------------------------------------------------------------------
extern "C" void kernel_launch(void* const* d_in, const int* in_sizes, int n_in,
                              void* d_out, int out_size, void* d_ws, size_t ws_size,
                              hipStream_t stream)
{
    const float* z   = (const float*)d_in[0];   // [65536,128]
    const float* emb = (const float*)d_in[1];   // [2048,128]
    float* out = (float*)d_out;                 // q(8388608) | idx-as-f32(65536) | loss(1)

    char*     ws       = (char*)d_ws;
    float*    enorm    = (float*)ws;                         // 2048 f32      @ 0
    float*    accum    = (float*)(ws + 8192);                // 1 f32
    int*      idx      = (int*)(ws + 16384);                 // 65536 i32     (256 KB)
    unsigned* cand_cnt = (unsigned*)(ws + 16384 + 262144);   // 65536 u32     (256 KB)
    ushort*   cand     = (ushort*)(ws + 16384 + 524288);     // 65536*CAP u16 (4 MB)

    prep_kernel   <<<NVEC / 256, 256, 0, stream>>>(emb, enorm, accum, cand_cnt);
    approx_kernel <<<256,        256, 0, stream>>>(z, emb, enorm, cand_cnt, cand);
    rerank_kernel <<<NVEC / 256, 256, 0, stream>>>(z, emb, enorm, cand_cnt, cand, idx);
    gather_kernel <<<NVEC / 8,   256, 0, stream>>>(z, emb, idx, out, out + 8388608, accum);
    finalize_kernel<<<1, 1, 0, stream>>>(accum, out + 8388608 + 65536);
}

// Round 5
// 2561.646 us; speedup vs baseline: 1.0151x; 1.0151x over previous
//
#include <hip/hip_runtime.h>

#define NUM_EMB 2048
#define DIM     128
#define NVEC    65536            // 64*32*32
#define MARGIN  4.0e-3f          // >= 4.6x worst-case bf16-approx error bound (validated R4: absmax 0)
#define CAP     32               // candidate cap per row; overflow -> exact full scan
#define CHUNK   256              // codes per LDS chunk in approx
#define NCHUNK  (NUM_EMB / CHUNK)
#define ES      136              // ushort stride/code in LDS: 272 B = 16B-aligned, ≡4 mod-32 banks (2-way, free)
#define ZS      132              // float stride/z-row in LDS: 528 B, same property

typedef float  f32x4 __attribute__((ext_vector_type(4)));
typedef short  s16x8 __attribute__((ext_vector_type(8)));

// RNE float -> bf16 (finite inputs)
__device__ __forceinline__ ushort f2bf(float f) {
    unsigned u = __float_as_uint(f);
    u = (u + 0x7fffu + ((u >> 16) & 1u)) >> 16;
    return (ushort)u;
}

// ---------------------------------------------------------------------------
// numpy pairwise_sum replica for n=128 fp32 applied to v*v (bit-exact vs np —
// verified R2/R3/R4 absmax 0.0).  DO NOT REASSOCIATE.
// ---------------------------------------------------------------------------
__device__ __forceinline__ float np_pairwise_sumsq_128(const float* __restrict__ p)
{
    float r[8];
    #pragma unroll
    for (int j = 0; j < 8; ++j) { float v = p[j]; r[j] = __fmul_rn(v, v); }
    #pragma unroll
    for (int i = 8; i < 128; i += 8)
        #pragma unroll
        for (int j = 0; j < 8; ++j) { float v = p[i + j]; r[j] = __fadd_rn(r[j], __fmul_rn(v, v)); }
    float s01 = __fadd_rn(r[0], r[1]);
    float s23 = __fadd_rn(r[2], r[3]);
    float s45 = __fadd_rn(r[4], r[5]);
    float s67 = __fadd_rn(r[6], r[7]);
    return __fadd_rn(__fadd_rn(s01, s23), __fadd_rn(s45, s67));
}

// ---------------------------------------------------------------------------
// Kernel 1: enorm (np-exact) + emb->bf16 + zero accum/cand_cnt.
// grid 256x256 = 65536 threads = one per float4 of emb and one per row-counter.
// ---------------------------------------------------------------------------
__global__ __launch_bounds__(256)
void prep_kernel(const float* __restrict__ emb,
                 float* __restrict__ enorm,
                 float* __restrict__ accum,
                 unsigned* __restrict__ cand_cnt,
                 ushort* __restrict__ emb_bf)
{
    int g = blockIdx.x * 256 + threadIdx.x;
    cand_cnt[g] = 0u;
    if (g == 0) *accum = 0.0f;

    float4 v = ((const float4*)emb)[g];          // 65536 float4 == full emb
    ushort4 b;
    b.x = f2bf(v.x); b.y = f2bf(v.y); b.z = f2bf(v.z); b.w = f2bf(v.w);
    ((ushort4*)emb_bf)[g] = b;

    if (g < NUM_EMB)
        enorm[g] = np_pairwise_sumsq_128(emb + (size_t)g * DIM);
}

// ---------------------------------------------------------------------------
// Kernel 2: bf16-MFMA approx scores, two passes (min, then margin-capture).
// Block 256 thr (4 waves); wave owns 64 rows; E chunks staged from emb_bf
// (pre-converted) with plain uint4 copies — no per-chunk f2bf.
// MFMA 16x16x32 bf16 layouts (HW-verified m89/m91).
// ---------------------------------------------------------------------------
__global__ __launch_bounds__(256, 1)
void approx_kernel(const float* __restrict__ z,
                   const ushort* __restrict__ emb_bf,
                   const float* __restrict__ enorm,
                   unsigned* __restrict__ cand_cnt,
                   ushort* __restrict__ cand)
{
    __shared__ __align__(16) ushort eS[CHUNK * ES];   // 69,632 B
    __shared__ float cS[CHUNK];

    const int tid  = threadIdx.x;
    const int w    = tid >> 6;
    const int lane = tid & 63;
    const int col  = lane & 15;           // m (A) / n (B) / D col
    const int quad = lane >> 4;           // k-group / D row-group
    const int rowbase = blockIdx.x * 256 + w * 64;

    // A-fragments: 4 row-tiles x 4 k-tiles, loaded once, fp32 -> bf16 RNE
    s16x8 afrag[4][4];
    #pragma unroll
    for (int rt = 0; rt < 4; ++rt) {
        const float* zr = z + (size_t)(rowbase + rt * 16 + col) * DIM;
        #pragma unroll
        for (int kt = 0; kt < 4; ++kt) {
            const float4* p = (const float4*)(zr + kt * 32 + quad * 8);
            float4 f0 = p[0], f1 = p[1];
            s16x8 a;
            a[0] = (short)f2bf(f0.x); a[1] = (short)f2bf(f0.y);
            a[2] = (short)f2bf(f0.z); a[3] = (short)f2bf(f0.w);
            a[4] = (short)f2bf(f1.x); a[5] = (short)f2bf(f1.y);
            a[6] = (short)f2bf(f1.z); a[7] = (short)f2bf(f1.w);
            afrag[rt][kt] = a;
        }
    }

    float minv[4][4];
    #pragma unroll
    for (int rt = 0; rt < 4; ++rt)
        #pragma unroll
        for (int r = 0; r < 4; ++r) minv[rt][r] = 3.0e38f;

    for (int pass = 0; pass < 2; ++pass) {
        for (int c = 0; c < NCHUNK; ++c) {
            __syncthreads();              // previous chunk's readers done
            // stage chunk: 256 codes x 128 bf16 = 64 KB, coalesced uint4 copies
            const uint4* src = (const uint4*)(emb_bf + (size_t)c * CHUNK * DIM);
            #pragma unroll
            for (int i = 0; i < 16; ++i) {
                int li   = i * 256 + tid;         // 0..4095
                int code = li >> 4, fc = li & 15;
                *(uint4*)&eS[code * ES + fc * 8] = src[li];
            }
            cS[tid] = enorm[c * CHUNK + tid];
            __syncthreads();

            for (int t = 0; t < 16; ++t) {
                s16x8 bfrag[4];
                #pragma unroll
                for (int kt = 0; kt < 4; ++kt)
                    bfrag[kt] = *(const s16x8*)&eS[(t * 16 + col) * ES + kt * 32 + quad * 8];

                f32x4 acc[4];
                #pragma unroll
                for (int rt = 0; rt < 4; ++rt) {
                    f32x4 a = {0.0f, 0.0f, 0.0f, 0.0f};
                    #pragma unroll
                    for (int kt = 0; kt < 4; ++kt)
                        a = __builtin_amdgcn_mfma_f32_16x16x32_bf16(afrag[rt][kt], bfrag[kt], a, 0, 0, 0);
                    acc[rt] = a;
                }

                float Cc     = cS[t * 16 + col];
                int   code_g = c * CHUNK + t * 16 + col;
                #pragma unroll
                for (int rt = 0; rt < 4; ++rt)
                    #pragma unroll
                    for (int r = 0; r < 4; ++r) {
                        float g = fmaf(-2.0f, acc[rt][r], Cc);
                        if (pass == 0) {
                            minv[rt][r] = fminf(minv[rt][r], g);
                        } else if (g <= minv[rt][r]) {      // minv holds min+MARGIN
                            int row_g = rowbase + rt * 16 + quad * 4 + r;
                            unsigned pos = atomicAdd(&cand_cnt[row_g], 1u);
                            if (pos < CAP) cand[(size_t)row_g * CAP + pos] = (ushort)code_g;
                        }
                    }
            }
        }
        if (pass == 0) {
            // butterfly min across the 16 cols of each quad -> per-row threshold
            #pragma unroll
            for (int rt = 0; rt < 4; ++rt)
                #pragma unroll
                for (int r = 0; r < 4; ++r) {
                    float v = minv[rt][r];
                    v = fminf(v, __shfl_xor(v, 1, 64));
                    v = fminf(v, __shfl_xor(v, 2, 64));
                    v = fminf(v, __shfl_xor(v, 4, 64));
                    v = fminf(v, __shfl_xor(v, 8, 64));
                    minv[rt][r] = v + MARGIN;
                }
        }
    }
}

// ---------------------------------------------------------------------------
// Kernel 3: exact fp32-replica re-rank + fused gather/loss epilogue.
// Block 256 thr <-> 64 rows; z tile in LDS (no per-thread private array — R4's
// rerank spilled zr[128] to scratch: 84 VGPR, occ 1.9%, 22.7 GB scratch FETCH).
// 4 lanes/row split candidates; each candidate's dot is a strictly sequential
// ascending-k single-accumulator fmaf chain (bit-exact — parallel over
// candidates, never over k). (val,idx) tie-reduce via shfl_xor.
// ---------------------------------------------------------------------------
__global__ __launch_bounds__(256)
void rerank_kernel(const float* __restrict__ z,
                   const float* __restrict__ emb,
                   const float* __restrict__ enorm,
                   const unsigned* __restrict__ cand_cnt,
                   const ushort* __restrict__ cand,
                   float* __restrict__ out_q,
                   float* __restrict__ out_idx_f,
                   float* __restrict__ accum)
{
    __shared__ float zs[64 * ZS];        // 33,792 B
    __shared__ float As[64];
    __shared__ int   bidx[64];
    __shared__ float wsum[4];

    const int tid = threadIdx.x;
    const int m0  = blockIdx.x * 64;

    // stage z tile, coalesced
    #pragma unroll
    for (int i = 0; i < 8; ++i) {
        int li = tid + i * 256;          // 0..2047
        int m  = li >> 5, dc = li & 31;
        float4 v = ((const float4*)(z + (size_t)(m0 + m) * DIM))[dc];
        *(float4*)&zs[m * ZS + dc * 4] = v;
    }
    __syncthreads();
    if (tid < 64) As[tid] = np_pairwise_sumsq_128(&zs[tid * ZS]);
    __syncthreads();

    const int row_l = tid >> 2;          // 0..63 (4 contiguous lanes per row)
    const int sub   = tid & 3;
    const int row_g = m0 + row_l;
    const unsigned cnt = cand_cnt[row_g];
    const float A = As[row_l];
    const float4* zp = (const float4*)&zs[row_l * ZS];

    float bv = 3.0e38f;
    int   bi = 0x7fffffff;

    if (cnt <= CAP) {
        for (unsigned ci = sub; ci < cnt; ci += 4) {
            int j = (int)cand[(size_t)row_g * CAP + ci];
            const float4* ep = (const float4*)(emb + (size_t)j * DIM);
            float dot = 0.0f;
            #pragma unroll
            for (int seg = 0; seg < 4; ++seg) {     // 32-k slabs, acc carries
                float4 e[8], zz[8];
                #pragma unroll
                for (int i = 0; i < 8; ++i) { e[i] = ep[seg * 8 + i]; zz[i] = zp[seg * 8 + i]; }
                #pragma unroll
                for (int i = 0; i < 8; ++i) {
                    dot = fmaf(zz[i].x, e[i].x, dot);
                    dot = fmaf(zz[i].y, e[i].y, dot);
                    dot = fmaf(zz[i].z, e[i].z, dot);
                    dot = fmaf(zz[i].w, e[i].w, dot);
                }
            }
            float t1 = fmaf(-2.0f, dot, A);
            float s  = __fadd_rn(t1, enorm[j]);
            if (s < bv || (s == bv && j < bi)) { bv = s; bi = j; }
        }
    } else if (sub == 0) {               // exact full scan (prob ~0)
        for (int j = 0; j < NUM_EMB; ++j) {
            const float4* ep = (const float4*)(emb + (size_t)j * DIM);
            float dot = 0.0f;
            #pragma unroll
            for (int seg = 0; seg < 4; ++seg) {
                float4 e[8], zz[8];
                #pragma unroll
                for (int i = 0; i < 8; ++i) { e[i] = ep[seg * 8 + i]; zz[i] = zp[seg * 8 + i]; }
                #pragma unroll
                for (int i = 0; i < 8; ++i) {
                    dot = fmaf(zz[i].x, e[i].x, dot);
                    dot = fmaf(zz[i].y, e[i].y, dot);
                    dot = fmaf(zz[i].z, e[i].z, dot);
                    dot = fmaf(zz[i].w, e[i].w, dot);
                }
            }
            float t1 = fmaf(-2.0f, dot, A);
            float s  = __fadd_rn(t1, enorm[j]);
            if (s < bv) { bv = s; bi = j; }
        }
    }

    // (val,idx) min-reduce across the 4 lanes of this row (same wave)
    #pragma unroll
    for (int off = 1; off <= 2; off <<= 1) {
        float v  = __shfl_xor(bv, off, 64);
        int   ix = __shfl_xor(bi, off, 64);
        if (v < bv || (v == bv && ix < bi)) { bv = v; bi = ix; }
    }
    if (sub == 0) {
        bidx[row_l] = bi;
        out_idx_f[row_g] = (float)bi;
    }
    __syncthreads();

    // fused gather + straight-through + loss partial (zs still intact)
    float part = 0.0f;
    #pragma unroll
    for (int i = 0; i < 8; ++i) {
        int li = tid + i * 256;
        int m  = li >> 5, dc = li & 31;
        int j  = bidx[m];
        float4 q  = ((const float4*)(emb + (size_t)j * DIM))[dc];
        float4 zv = *(const float4*)&zs[m * ZS + dc * 4];
        float4 o;
        o.x = __fadd_rn(zv.x, __fsub_rn(q.x, zv.x));
        o.y = __fadd_rn(zv.y, __fsub_rn(q.y, zv.y));
        o.z = __fadd_rn(zv.z, __fsub_rn(q.z, zv.z));
        o.w = __fadd_rn(zv.w, __fsub_rn(q.w, zv.w));
        ((float4*)out_q)[(size_t)(m0 + m) * 32 + dc] = o;
        float dx = q.x - zv.x, dy = q.y - zv.y, dz = q.z - zv.z, dw = q.w - zv.w;
        part += dx * dx + dy * dy + dz * dz + dw * dw;
    }
    #pragma unroll
    for (int off = 32; off > 0; off >>= 1)
        part += __shfl_down(part, off, 64);
    if ((tid & 63) == 0) wsum[tid >> 6] = part;
    __syncthreads();
    if (tid == 0) atomicAdd(accum, wsum[0] + wsum[1] + wsum[2] + wsum[3]);
}

// ---------------------------------------------------------------------------
// Kernel 4: loss = (1 + beta) * sum / (N*D), beta = 0.25
// ---------------------------------------------------------------------------
__global__ void finalize_kernel(const float* __restrict__ accum,
                                float* __restrict__ out_loss)
{
    *out_loss = 1.25f * (*accum) / 8388608.0f;
}

// ---------------------------------------------------------------------------
extern "C" void kernel_launch(void* const* d_in, const int* in_sizes, int n_in,
                              void* d_out, int out_size, void* d_ws, size_t ws_size,
                              hipStream_t stream)
{
    const float* z   = (const float*)d_in[0];   // [65536,128]
    const float* emb = (const float*)d_in[1];   // [2048,128]
    float* out = (float*)d_out;                 // q(8388608) | idx-as-f32(65536) | loss(1)

    char*     ws       = (char*)d_ws;
    float*    enorm    = (float*)ws;                          // 8 KB
    float*    accum    = (float*)(ws + 8192);
    unsigned* cand_cnt = (unsigned*)(ws + 16384);             // 256 KB
    ushort*   cand     = (ushort*)(ws + 16384 + 262144);      // 4 MB
    ushort*   emb_bf   = (ushort*)(ws + 16384 + 262144 + 4194304);  // 512 KB

    prep_kernel   <<<NVEC / 256, 256, 0, stream>>>(emb, enorm, accum, cand_cnt, emb_bf);
    approx_kernel <<<256,        256, 0, stream>>>(z, emb_bf, enorm, cand_cnt, cand);
    rerank_kernel <<<NVEC / 64,  256, 0, stream>>>(z, emb, enorm, cand_cnt, cand,
                                                   out, out + 8388608, accum);
    finalize_kernel<<<1, 1, 0, stream>>>(accum, out + 8388608 + 65536);
}

// Round 6
// 2404.408 us; speedup vs baseline: 1.0815x; 1.0654x over previous
//
#include <hip/hip_runtime.h>

#define NUM_EMB 2048
#define DIM     128
#define NVEC    65536            // 64*32*32
#define MARGIN  4.0e-3f          // ~5-10x worst-case bf16-approx error bound (coverage proven R4/R5)
#define CAP     32               // stored candidates per row; overflow -> cooperative block scan
#define CHUNK   256              // codes per LDS chunk in approx
#define NCHUNK  (NUM_EMB / CHUNK)
#define ES      136              // ushort stride/code in LDS: 272 B, 16B-aligned, 2-way banks (free)
#define ZS      132              // float stride/z-row in LDS

typedef float  f32x4 __attribute__((ext_vector_type(4)));
typedef short  s16x8 __attribute__((ext_vector_type(8)));

// RNE float -> bf16 (finite inputs)
__device__ __forceinline__ ushort f2bf(float f) {
    unsigned u = __float_as_uint(f);
    u = (u + 0x7fffu + ((u >> 16) & 1u)) >> 16;
    return (ushort)u;
}

// ---------------------------------------------------------------------------
// numpy pairwise_sum replica for n=128 fp32 applied to v*v (bit-exact vs np —
// verified R2-R5 absmax 0.0).  DO NOT REASSOCIATE.
// ---------------------------------------------------------------------------
__device__ __forceinline__ float np_pairwise_sumsq_128(const float* __restrict__ p)
{
    float r[8];
    #pragma unroll
    for (int j = 0; j < 8; ++j) { float v = p[j]; r[j] = __fmul_rn(v, v); }
    #pragma unroll
    for (int i = 8; i < 128; i += 8)
        #pragma unroll
        for (int j = 0; j < 8; ++j) { float v = p[i + j]; r[j] = __fadd_rn(r[j], __fmul_rn(v, v)); }
    float s01 = __fadd_rn(r[0], r[1]);
    float s23 = __fadd_rn(r[2], r[3]);
    float s45 = __fadd_rn(r[4], r[5]);
    float s67 = __fadd_rn(r[6], r[7]);
    return __fadd_rn(__fadd_rn(s01, s23), __fadd_rn(s45, s67));
}

// exact fp32-replica dot over one 32-k slab (ascending k, single accumulator)
__device__ __forceinline__ float dot_seg(const float4* __restrict__ zp,
                                         const float4* __restrict__ ep,
                                         int seg, float dot)
{
    float4 e[8], zz[8];
    #pragma unroll
    for (int i = 0; i < 8; ++i) { e[i] = ep[seg * 8 + i]; zz[i] = zp[seg * 8 + i]; }
    #pragma unroll
    for (int i = 0; i < 8; ++i) {
        dot = fmaf(zz[i].x, e[i].x, dot);
        dot = fmaf(zz[i].y, e[i].y, dot);
        dot = fmaf(zz[i].z, e[i].z, dot);
        dot = fmaf(zz[i].w, e[i].w, dot);
    }
    return dot;
}

// ---------------------------------------------------------------------------
// Kernel 1: enorm (np-exact) + emb->bf16 + zero accum/cand_cnt
// ---------------------------------------------------------------------------
__global__ __launch_bounds__(256)
void prep_kernel(const float* __restrict__ emb,
                 float* __restrict__ enorm,
                 float* __restrict__ accum,
                 unsigned* __restrict__ cand_cnt,
                 ushort* __restrict__ emb_bf)
{
    int g = blockIdx.x * 256 + threadIdx.x;
    cand_cnt[g] = 0u;
    if (g == 0) *accum = 0.0f;

    float4 v = ((const float4*)emb)[g];          // 65536 float4 == full emb
    ushort4 b;
    b.x = f2bf(v.x); b.y = f2bf(v.y); b.z = f2bf(v.z); b.w = f2bf(v.w);
    ((ushort4*)emb_bf)[g] = b;

    if (g < NUM_EMB)
        enorm[g] = np_pairwise_sumsq_128(emb + (size_t)g * DIM);
}

// ---------------------------------------------------------------------------
// Kernel 2: bf16-MFMA approx filter, SINGLE capture pass.
// Seed: chunk 0 min-only -> row threshold (butterfly + MARGIN). Capture pass
// over all 8 chunks with running row-threshold refreshed after each chunk.
// Running threshold >= final_min + MARGIN at all times => captured set is a
// SUPERSET of the true margin set (no misses; over-capture is handled by the
// rerank overflow scan).  MFMA 16x16x32 bf16 layouts HW-verified (m89/m91).
// ---------------------------------------------------------------------------
__global__ __launch_bounds__(256, 1)
void approx_kernel(const float* __restrict__ z,
                   const ushort* __restrict__ emb_bf,
                   const float* __restrict__ enorm,
                   unsigned* __restrict__ cand_cnt,
                   ushort* __restrict__ cand)
{
    __shared__ __align__(16) ushort eS[CHUNK * ES];   // 69,632 B
    __shared__ float cS[CHUNK];

    const int tid  = threadIdx.x;
    const int w    = tid >> 6;
    const int lane = tid & 63;
    const int col  = lane & 15;           // m (A frag) / n (B frag) / D col
    const int quad = lane >> 4;           // k-group / D row-group
    const int rowbase = blockIdx.x * 256 + w * 64;

    // A-fragments: 4 row-tiles x 4 k-tiles, loaded once, fp32 -> bf16 RNE
    s16x8 afrag[4][4];
    #pragma unroll
    for (int rt = 0; rt < 4; ++rt) {
        const float* zr = z + (size_t)(rowbase + rt * 16 + col) * DIM;
        #pragma unroll
        for (int kt = 0; kt < 4; ++kt) {
            const float4* p = (const float4*)(zr + kt * 32 + quad * 8);
            float4 f0 = p[0], f1 = p[1];
            s16x8 a;
            a[0] = (short)f2bf(f0.x); a[1] = (short)f2bf(f0.y);
            a[2] = (short)f2bf(f0.z); a[3] = (short)f2bf(f0.w);
            a[4] = (short)f2bf(f1.x); a[5] = (short)f2bf(f1.y);
            a[6] = (short)f2bf(f1.z); a[7] = (short)f2bf(f1.w);
            afrag[rt][kt] = a;
        }
    }

    float minv[4][4], thr[4][4];
    #pragma unroll
    for (int rt = 0; rt < 4; ++rt)
        #pragma unroll
        for (int r = 0; r < 4; ++r) minv[rt][r] = 3.0e38f;

    // 9 chunk-visits: visit 0 = seed (chunk 0, min only), visits 1..8 = capture
    for (int vis = 0; vis < 9; ++vis) {
        const int c = (vis == 0) ? 0 : (vis - 1);
        __syncthreads();                 // previous chunk's readers done
        const uint4* src = (const uint4*)(emb_bf + (size_t)c * CHUNK * DIM);
        #pragma unroll
        for (int i = 0; i < 16; ++i) {
            int li   = i * 256 + tid;             // 0..4095
            int code = li >> 4, fc = li & 15;
            *(uint4*)&eS[code * ES + fc * 8] = src[li];
        }
        cS[tid] = enorm[c * CHUNK + tid];
        __syncthreads();

        for (int t = 0; t < 16; ++t) {
            s16x8 bfrag[4];
            #pragma unroll
            for (int kt = 0; kt < 4; ++kt)
                bfrag[kt] = *(const s16x8*)&eS[(t * 16 + col) * ES + kt * 32 + quad * 8];

            f32x4 acc[4];
            #pragma unroll
            for (int rt = 0; rt < 4; ++rt) {
                f32x4 a = {0.0f, 0.0f, 0.0f, 0.0f};
                #pragma unroll
                for (int kt = 0; kt < 4; ++kt)
                    a = __builtin_amdgcn_mfma_f32_16x16x32_bf16(afrag[rt][kt], bfrag[kt], a, 0, 0, 0);
                acc[rt] = a;
            }

            float Cc     = cS[t * 16 + col];
            int   code_g = c * CHUNK + t * 16 + col;
            #pragma unroll
            for (int rt = 0; rt < 4; ++rt)
                #pragma unroll
                for (int r = 0; r < 4; ++r) {
                    float g = fmaf(-2.0f, acc[rt][r], Cc);
                    minv[rt][r] = fminf(minv[rt][r], g);
                    if (vis > 0 && g <= thr[rt][r]) {
                        int row_g = rowbase + rt * 16 + quad * 4 + r;
                        unsigned pos = atomicAdd(&cand_cnt[row_g], 1u);
                        if (pos < CAP) cand[(size_t)row_g * CAP + pos] = (ushort)code_g;
                    }
                }
        }

        // refresh row-wide threshold: butterfly min across the 16 cols
        #pragma unroll
        for (int rt = 0; rt < 4; ++rt)
            #pragma unroll
            for (int r = 0; r < 4; ++r) {
                float v = minv[rt][r];
                v = fminf(v, __shfl_xor(v, 1, 64));
                v = fminf(v, __shfl_xor(v, 2, 64));
                v = fminf(v, __shfl_xor(v, 4, 64));
                v = fminf(v, __shfl_xor(v, 8, 64));
                minv[rt][r] = v;
                thr[rt][r]  = v + MARGIN;
            }
    }
}

// ---------------------------------------------------------------------------
// Kernel 3: exact fp32-replica re-rank + cooperative overflow scan + fused
// gather/loss epilogue.  R4/R5 lesson: the single-lane 2048-code fallback
// serialized ~2.5 ms on a handful of overflow rows — now the whole block
// scans each overflow row (8 ascending codes/thread, (v,idx)-tie reduce),
// ~2 us/row, worst case bounded ~300 us.
// ---------------------------------------------------------------------------
__global__ __launch_bounds__(256)
void rerank_kernel(const float* __restrict__ z,
                   const float* __restrict__ emb,
                   const float* __restrict__ enorm,
                   const unsigned* __restrict__ cand_cnt,
                   const ushort* __restrict__ cand,
                   float* __restrict__ out_q,
                   float* __restrict__ out_idx_f,
                   float* __restrict__ accum)
{
    __shared__ float zs[64 * ZS];        // 33,792 B
    __shared__ float As[64];
    __shared__ int   bidx[64];
    __shared__ int   ovf_list[64];
    __shared__ int   ovf_n;
    __shared__ float rv[4];
    __shared__ int   rvi[4];
    __shared__ float wsum[4];

    const int tid = threadIdx.x;
    const int m0  = blockIdx.x * 64;
    if (tid == 0) ovf_n = 0;

    // stage z tile, coalesced
    #pragma unroll
    for (int i = 0; i < 8; ++i) {
        int li = tid + i * 256;          // 0..2047
        int m  = li >> 5, dc = li & 31;
        float4 v = ((const float4*)(z + (size_t)(m0 + m) * DIM))[dc];
        *(float4*)&zs[m * ZS + dc * 4] = v;
    }
    __syncthreads();
    if (tid < 64) As[tid] = np_pairwise_sumsq_128(&zs[tid * ZS]);
    __syncthreads();

    const int row_l = tid >> 2;          // 4 contiguous lanes per row
    const int sub   = tid & 3;
    const int row_g = m0 + row_l;
    const unsigned cnt = cand_cnt[row_g];
    const float A = As[row_l];
    const float4* zp = (const float4*)&zs[row_l * ZS];

    float bv = 3.0e38f;
    int   bi = 0x7fffffff;

    if (cnt <= CAP) {                    // candidate path (split over 4 lanes)
        for (unsigned ci = sub; ci < cnt; ci += 4) {
            int j = (int)cand[(size_t)row_g * CAP + ci];
            const float4* ep = (const float4*)(emb + (size_t)j * DIM);
            float dot = 0.0f;
            #pragma unroll
            for (int seg = 0; seg < 4; ++seg) dot = dot_seg(zp, ep, seg, dot);
            float t1 = fmaf(-2.0f, dot, A);
            float s  = __fadd_rn(t1, enorm[j]);
            if (s < bv || (s == bv && j < bi)) { bv = s; bi = j; }
        }
    }
    // (val,idx) min-reduce across the 4 lanes of this row
    #pragma unroll
    for (int off = 1; off <= 2; off <<= 1) {
        float v  = __shfl_xor(bv, off, 64);
        int   ix = __shfl_xor(bi, off, 64);
        if (v < bv || (v == bv && ix < bi)) { bv = v; bi = ix; }
    }
    if (sub == 0) {
        if (cnt <= CAP) bidx[row_l] = bi;
        else { int p = atomicAdd(&ovf_n, 1); ovf_list[p] = row_l; }
    }
    __syncthreads();

    // cooperative exact scan of overflow rows: 256 thr x 8 ascending codes
    const int n_ovf = ovf_n;
    for (int o = 0; o < n_ovf; ++o) {
        const int rl = ovf_list[o];
        const float Ar = As[rl];
        const float4* zp2 = (const float4*)&zs[rl * ZS];
        float bv2 = 3.0e38f;
        int   bi2 = 0x7fffffff;
        for (int jj = 0; jj < 8; ++jj) {
            int j = tid * 8 + jj;        // ascending within thread -> strict <
            const float4* ep = (const float4*)(emb + (size_t)j * DIM);
            float dot = 0.0f;
            #pragma unroll
            for (int seg = 0; seg < 4; ++seg) dot = dot_seg(zp2, ep, seg, dot);
            float t1 = fmaf(-2.0f, dot, Ar);
            float s  = __fadd_rn(t1, enorm[j]);
            if (s < bv2) { bv2 = s; bi2 = j; }
        }
        #pragma unroll
        for (int off = 1; off < 64; off <<= 1) {
            float v  = __shfl_xor(bv2, off, 64);
            int   ix = __shfl_xor(bi2, off, 64);
            if (v < bv2 || (v == bv2 && ix < bi2)) { bv2 = v; bi2 = ix; }
        }
        if ((tid & 63) == 0) { rv[tid >> 6] = bv2; rvi[tid >> 6] = bi2; }
        __syncthreads();
        if (tid == 0) {
            float fv = rv[0]; int fi = rvi[0];
            #pragma unroll
            for (int ww = 1; ww < 4; ++ww) {
                if (rv[ww] < fv || (rv[ww] == fv && rvi[ww] < fi)) { fv = rv[ww]; fi = rvi[ww]; }
            }
            bidx[rl] = fi;
        }
        __syncthreads();
    }

    if (tid < 64) out_idx_f[m0 + tid] = (float)bidx[tid];

    // fused gather + straight-through + loss partial (zs still intact)
    float part = 0.0f;
    #pragma unroll
    for (int i = 0; i < 8; ++i) {
        int li = tid + i * 256;
        int m  = li >> 5, dc = li & 31;
        int j  = bidx[m];
        float4 q  = ((const float4*)(emb + (size_t)j * DIM))[dc];
        float4 zv = *(const float4*)&zs[m * ZS + dc * 4];
        float4 o;
        o.x = __fadd_rn(zv.x, __fsub_rn(q.x, zv.x));
        o.y = __fadd_rn(zv.y, __fsub_rn(q.y, zv.y));
        o.z = __fadd_rn(zv.z, __fsub_rn(q.z, zv.z));
        o.w = __fadd_rn(zv.w, __fsub_rn(q.w, zv.w));
        ((float4*)out_q)[(size_t)(m0 + m) * 32 + dc] = o;
        float dx = q.x - zv.x, dy = q.y - zv.y, dz = q.z - zv.z, dw = q.w - zv.w;
        part += dx * dx + dy * dy + dz * dz + dw * dw;
    }
    #pragma unroll
    for (int off = 32; off > 0; off >>= 1)
        part += __shfl_down(part, off, 64);
    if ((tid & 63) == 0) wsum[tid >> 6] = part;
    __syncthreads();
    if (tid == 0) atomicAdd(accum, wsum[0] + wsum[1] + wsum[2] + wsum[3]);
}

// ---------------------------------------------------------------------------
// Kernel 4: loss = (1 + beta) * sum / (N*D), beta = 0.25
// ---------------------------------------------------------------------------
__global__ void finalize_kernel(const float* __restrict__ accum,
                                float* __restrict__ out_loss)
{
    *out_loss = 1.25f * (*accum) / 8388608.0f;
}

// ---------------------------------------------------------------------------
extern "C" void kernel_launch(void* const* d_in, const int* in_sizes, int n_in,
                              void* d_out, int out_size, void* d_ws, size_t ws_size,
                              hipStream_t stream)
{
    const float* z   = (const float*)d_in[0];   // [65536,128]
    const float* emb = (const float*)d_in[1];   // [2048,128]
    float* out = (float*)d_out;                 // q(8388608) | idx-as-f32(65536) | loss(1)

    char*     ws       = (char*)d_ws;
    float*    enorm    = (float*)ws;                          // 8 KB
    float*    accum    = (float*)(ws + 8192);
    unsigned* cand_cnt = (unsigned*)(ws + 16384);             // 256 KB
    ushort*   cand     = (ushort*)(ws + 16384 + 262144);      // 4 MB
    ushort*   emb_bf   = (ushort*)(ws + 16384 + 262144 + 4194304);  // 512 KB

    prep_kernel   <<<NVEC / 256, 256, 0, stream>>>(emb, enorm, accum, cand_cnt, emb_bf);
    approx_kernel <<<256,        256, 0, stream>>>(z, emb_bf, enorm, cand_cnt, cand);
    rerank_kernel <<<NVEC / 64,  256, 0, stream>>>(z, emb, enorm, cand_cnt, cand,
                                                   out, out + 8388608, accum);
    finalize_kernel<<<1, 1, 0, stream>>>(accum, out + 8388608 + 65536);
}

// Round 7
// 395.754 us; speedup vs baseline: 6.5704x; 6.0755x over previous
//
#include <hip/hip_runtime.h>

#define NUM_EMB 2048
#define DIM     128
#define NVEC    65536            // 64*32*32
// MARGIN: needs >= 2*approx_err + fp32-bucket slop. Approx err is a zero-mean
// sum of 256 indep bf16-rounding terms, std ~9e-6 -> 8-sigma over 134M dots
// ~1e-4; buckets (ulp(128)) add 6e-5. 1e-3 = 4x headroom. R6's 4e-3 (worst-
// case Cauchy-Schwarz) over-captured ~10-25 codes/row -> divergent-gather +
// overflow-scan wall (rerank 1.9-2.6 ms across R4/R5/R6).
#define MARGIN  1.0e-3f
#define CAP     32               // candidates/row; overflow -> cooperative block scan (now ~dead)
#define CHUNK   256              // codes per LDS chunk in approx
#define NCHUNK  (NUM_EMB / CHUNK)
#define ES      136              // ushort stride/code in LDS: 272 B, 16B-aligned, 2-way banks (free)
#define ZS      132              // float stride/z-row in LDS

typedef float  f32x4 __attribute__((ext_vector_type(4)));
typedef short  s16x8 __attribute__((ext_vector_type(8)));

// RNE float -> bf16 (finite inputs)
__device__ __forceinline__ ushort f2bf(float f) {
    unsigned u = __float_as_uint(f);
    u = (u + 0x7fffu + ((u >> 16) & 1u)) >> 16;
    return (ushort)u;
}

// ---------------------------------------------------------------------------
// numpy pairwise_sum replica for n=128 fp32 applied to v*v (bit-exact vs np —
// verified R2-R6 absmax 0.0).  DO NOT REASSOCIATE.
// ---------------------------------------------------------------------------
__device__ __forceinline__ float np_pairwise_sumsq_128(const float* __restrict__ p)
{
    float r[8];
    #pragma unroll
    for (int j = 0; j < 8; ++j) { float v = p[j]; r[j] = __fmul_rn(v, v); }
    #pragma unroll
    for (int i = 8; i < 128; i += 8)
        #pragma unroll
        for (int j = 0; j < 8; ++j) { float v = p[i + j]; r[j] = __fadd_rn(r[j], __fmul_rn(v, v)); }
    float s01 = __fadd_rn(r[0], r[1]);
    float s23 = __fadd_rn(r[2], r[3]);
    float s45 = __fadd_rn(r[4], r[5]);
    float s67 = __fadd_rn(r[6], r[7]);
    return __fadd_rn(__fadd_rn(s01, s23), __fadd_rn(s45, s67));
}

// exact fp32-replica dot over one 32-k slab (ascending k, single accumulator)
__device__ __forceinline__ float dot_seg(const float4* __restrict__ zp,
                                         const float4* __restrict__ ep,
                                         int seg, float dot)
{
    float4 e[8], zz[8];
    #pragma unroll
    for (int i = 0; i < 8; ++i) { e[i] = ep[seg * 8 + i]; zz[i] = zp[seg * 8 + i]; }
    #pragma unroll
    for (int i = 0; i < 8; ++i) {
        dot = fmaf(zz[i].x, e[i].x, dot);
        dot = fmaf(zz[i].y, e[i].y, dot);
        dot = fmaf(zz[i].z, e[i].z, dot);
        dot = fmaf(zz[i].w, e[i].w, dot);
    }
    return dot;
}

// ---------------------------------------------------------------------------
// Kernel 1: enorm (np-exact) + emb->bf16 + zero accum/cand_cnt
// ---------------------------------------------------------------------------
__global__ __launch_bounds__(256)
void prep_kernel(const float* __restrict__ emb,
                 float* __restrict__ enorm,
                 float* __restrict__ accum,
                 unsigned* __restrict__ cand_cnt,
                 ushort* __restrict__ emb_bf)
{
    int g = blockIdx.x * 256 + threadIdx.x;
    cand_cnt[g] = 0u;
    if (g == 0) *accum = 0.0f;

    float4 v = ((const float4*)emb)[g];          // 65536 float4 == full emb
    ushort4 b;
    b.x = f2bf(v.x); b.y = f2bf(v.y); b.z = f2bf(v.z); b.w = f2bf(v.w);
    ((ushort4*)emb_bf)[g] = b;

    if (g < NUM_EMB)
        enorm[g] = np_pairwise_sumsq_128(emb + (size_t)g * DIM);
}

// ---------------------------------------------------------------------------
// Kernel 2: bf16-MFMA approx filter, single capture pass with running
// row-threshold (seed visit on chunk 0).  Captured set is a superset of the
// true margin set.  MFMA 16x16x32 bf16 layouts HW-verified (m89/m91).
// ---------------------------------------------------------------------------
__global__ __launch_bounds__(256, 1)
void approx_kernel(const float* __restrict__ z,
                   const ushort* __restrict__ emb_bf,
                   const float* __restrict__ enorm,
                   unsigned* __restrict__ cand_cnt,
                   ushort* __restrict__ cand)
{
    __shared__ __align__(16) ushort eS[CHUNK * ES];   // 69,632 B
    __shared__ float cS[CHUNK];

    const int tid  = threadIdx.x;
    const int w    = tid >> 6;
    const int lane = tid & 63;
    const int col  = lane & 15;           // m (A frag) / n (B frag) / D col
    const int quad = lane >> 4;           // k-group / D row-group
    const int rowbase = blockIdx.x * 256 + w * 64;

    // A-fragments: 4 row-tiles x 4 k-tiles, loaded once, fp32 -> bf16 RNE
    s16x8 afrag[4][4];
    #pragma unroll
    for (int rt = 0; rt < 4; ++rt) {
        const float* zr = z + (size_t)(rowbase + rt * 16 + col) * DIM;
        #pragma unroll
        for (int kt = 0; kt < 4; ++kt) {
            const float4* p = (const float4*)(zr + kt * 32 + quad * 8);
            float4 f0 = p[0], f1 = p[1];
            s16x8 a;
            a[0] = (short)f2bf(f0.x); a[1] = (short)f2bf(f0.y);
            a[2] = (short)f2bf(f0.z); a[3] = (short)f2bf(f0.w);
            a[4] = (short)f2bf(f1.x); a[5] = (short)f2bf(f1.y);
            a[6] = (short)f2bf(f1.z); a[7] = (short)f2bf(f1.w);
            afrag[rt][kt] = a;
        }
    }

    float minv[4][4], thr[4][4];
    #pragma unroll
    for (int rt = 0; rt < 4; ++rt)
        #pragma unroll
        for (int r = 0; r < 4; ++r) minv[rt][r] = 3.0e38f;

    // 9 chunk-visits: visit 0 = seed (chunk 0, min only), visits 1..8 = capture
    for (int vis = 0; vis < 9; ++vis) {
        const int c = (vis == 0) ? 0 : (vis - 1);
        __syncthreads();                 // previous chunk's readers done
        const uint4* src = (const uint4*)(emb_bf + (size_t)c * CHUNK * DIM);
        #pragma unroll
        for (int i = 0; i < 16; ++i) {
            int li   = i * 256 + tid;             // 0..4095
            int code = li >> 4, fc = li & 15;
            *(uint4*)&eS[code * ES + fc * 8] = src[li];
        }
        cS[tid] = enorm[c * CHUNK + tid];
        __syncthreads();

        for (int t = 0; t < 16; ++t) {
            s16x8 bfrag[4];
            #pragma unroll
            for (int kt = 0; kt < 4; ++kt)
                bfrag[kt] = *(const s16x8*)&eS[(t * 16 + col) * ES + kt * 32 + quad * 8];

            f32x4 acc[4];
            #pragma unroll
            for (int rt = 0; rt < 4; ++rt) {
                f32x4 a = {0.0f, 0.0f, 0.0f, 0.0f};
                #pragma unroll
                for (int kt = 0; kt < 4; ++kt)
                    a = __builtin_amdgcn_mfma_f32_16x16x32_bf16(afrag[rt][kt], bfrag[kt], a, 0, 0, 0);
                acc[rt] = a;
            }

            float Cc     = cS[t * 16 + col];
            int   code_g = c * CHUNK + t * 16 + col;
            #pragma unroll
            for (int rt = 0; rt < 4; ++rt)
                #pragma unroll
                for (int r = 0; r < 4; ++r) {
                    float g = fmaf(-2.0f, acc[rt][r], Cc);
                    minv[rt][r] = fminf(minv[rt][r], g);
                    if (vis > 0 && g <= thr[rt][r]) {
                        int row_g = rowbase + rt * 16 + quad * 4 + r;
                        unsigned pos = atomicAdd(&cand_cnt[row_g], 1u);
                        if (pos < CAP) cand[(size_t)row_g * CAP + pos] = (ushort)code_g;
                    }
                }
        }

        // refresh row-wide threshold: butterfly min across the 16 cols
        #pragma unroll
        for (int rt = 0; rt < 4; ++rt)
            #pragma unroll
            for (int r = 0; r < 4; ++r) {
                float v = minv[rt][r];
                v = fminf(v, __shfl_xor(v, 1, 64));
                v = fminf(v, __shfl_xor(v, 2, 64));
                v = fminf(v, __shfl_xor(v, 4, 64));
                v = fminf(v, __shfl_xor(v, 8, 64));
                minv[rt][r] = v;
                thr[rt][r]  = v + MARGIN;
            }
    }
}

// ---------------------------------------------------------------------------
// Kernel 3: exact fp32-replica re-rank + cooperative overflow scan + fused
// gather/loss epilogue (structure identical to R6 — this round changes only
// MARGIN, to isolate the Sigma-cnt variable).
// ---------------------------------------------------------------------------
__global__ __launch_bounds__(256)
void rerank_kernel(const float* __restrict__ z,
                   const float* __restrict__ emb,
                   const float* __restrict__ enorm,
                   const unsigned* __restrict__ cand_cnt,
                   const ushort* __restrict__ cand,
                   float* __restrict__ out_q,
                   float* __restrict__ out_idx_f,
                   float* __restrict__ accum)
{
    __shared__ float zs[64 * ZS];        // 33,792 B
    __shared__ float As[64];
    __shared__ int   bidx[64];
    __shared__ int   ovf_list[64];
    __shared__ int   ovf_n;
    __shared__ float rv[4];
    __shared__ int   rvi[4];
    __shared__ float wsum[4];

    const int tid = threadIdx.x;
    const int m0  = blockIdx.x * 64;
    if (tid == 0) ovf_n = 0;

    // stage z tile, coalesced
    #pragma unroll
    for (int i = 0; i < 8; ++i) {
        int li = tid + i * 256;          // 0..2047
        int m  = li >> 5, dc = li & 31;
        float4 v = ((const float4*)(z + (size_t)(m0 + m) * DIM))[dc];
        *(float4*)&zs[m * ZS + dc * 4] = v;
    }
    __syncthreads();
    if (tid < 64) As[tid] = np_pairwise_sumsq_128(&zs[tid * ZS]);
    __syncthreads();

    const int row_l = tid >> 2;          // 4 contiguous lanes per row
    const int sub   = tid & 3;
    const int row_g = m0 + row_l;
    const unsigned cnt = cand_cnt[row_g];
    const float A = As[row_l];
    const float4* zp = (const float4*)&zs[row_l * ZS];

    float bv = 3.0e38f;
    int   bi = 0x7fffffff;

    if (cnt <= CAP) {                    // candidate path (split over 4 lanes)
        for (unsigned ci = sub; ci < cnt; ci += 4) {
            int j = (int)cand[(size_t)row_g * CAP + ci];
            const float4* ep = (const float4*)(emb + (size_t)j * DIM);
            float dot = 0.0f;
            #pragma unroll
            for (int seg = 0; seg < 4; ++seg) dot = dot_seg(zp, ep, seg, dot);
            float t1 = fmaf(-2.0f, dot, A);
            float s  = __fadd_rn(t1, enorm[j]);
            if (s < bv || (s == bv && j < bi)) { bv = s; bi = j; }
        }
    }
    // (val,idx) min-reduce across the 4 lanes of this row
    #pragma unroll
    for (int off = 1; off <= 2; off <<= 1) {
        float v  = __shfl_xor(bv, off, 64);
        int   ix = __shfl_xor(bi, off, 64);
        if (v < bv || (v == bv && ix < bi)) { bv = v; bi = ix; }
    }
    if (sub == 0) {
        if (cnt <= CAP) bidx[row_l] = bi;
        else { int p = atomicAdd(&ovf_n, 1); ovf_list[p] = row_l; }
    }
    __syncthreads();

    // cooperative exact scan of overflow rows: 256 thr x 8 ascending codes
    const int n_ovf = ovf_n;
    for (int o = 0; o < n_ovf; ++o) {
        const int rl = ovf_list[o];
        const float Ar = As[rl];
        const float4* zp2 = (const float4*)&zs[rl * ZS];
        float bv2 = 3.0e38f;
        int   bi2 = 0x7fffffff;
        for (int jj = 0; jj < 8; ++jj) {
            int j = tid * 8 + jj;        // ascending within thread -> strict <
            const float4* ep = (const float4*)(emb + (size_t)j * DIM);
            float dot = 0.0f;
            #pragma unroll
            for (int seg = 0; seg < 4; ++seg) dot = dot_seg(zp2, ep, seg, dot);
            float t1 = fmaf(-2.0f, dot, Ar);
            float s  = __fadd_rn(t1, enorm[j]);
            if (s < bv2) { bv2 = s; bi2 = j; }
        }
        #pragma unroll
        for (int off = 1; off < 64; off <<= 1) {
            float v  = __shfl_xor(bv2, off, 64);
            int   ix = __shfl_xor(bi2, off, 64);
            if (v < bv2 || (v == bv2 && ix < bi2)) { bv2 = v; bi2 = ix; }
        }
        if ((tid & 63) == 0) { rv[tid >> 6] = bv2; rvi[tid >> 6] = bi2; }
        __syncthreads();
        if (tid == 0) {
            float fv = rv[0]; int fi = rvi[0];
            #pragma unroll
            for (int ww = 1; ww < 4; ++ww) {
                if (rv[ww] < fv || (rv[ww] == fv && rvi[ww] < fi)) { fv = rv[ww]; fi = rvi[ww]; }
            }
            bidx[rl] = fi;
        }
        __syncthreads();
    }

    if (tid < 64) out_idx_f[m0 + tid] = (float)bidx[tid];

    // fused gather + straight-through + loss partial (zs still intact)
    float part = 0.0f;
    #pragma unroll
    for (int i = 0; i < 8; ++i) {
        int li = tid + i * 256;
        int m  = li >> 5, dc = li & 31;
        int j  = bidx[m];
        float4 q  = ((const float4*)(emb + (size_t)j * DIM))[dc];
        float4 zv = *(const float4*)&zs[m * ZS + dc * 4];
        float4 o;
        o.x = __fadd_rn(zv.x, __fsub_rn(q.x, zv.x));
        o.y = __fadd_rn(zv.y, __fsub_rn(q.y, zv.y));
        o.z = __fadd_rn(zv.z, __fsub_rn(q.z, zv.z));
        o.w = __fadd_rn(zv.w, __fsub_rn(q.w, zv.w));
        ((float4*)out_q)[(size_t)(m0 + m) * 32 + dc] = o;
        float dx = q.x - zv.x, dy = q.y - zv.y, dz = q.z - zv.z, dw = q.w - zv.w;
        part += dx * dx + dy * dy + dz * dz + dw * dw;
    }
    #pragma unroll
    for (int off = 32; off > 0; off >>= 1)
        part += __shfl_down(part, off, 64);
    if ((tid & 63) == 0) wsum[tid >> 6] = part;
    __syncthreads();
    if (tid == 0) atomicAdd(accum, wsum[0] + wsum[1] + wsum[2] + wsum[3]);
}

// ---------------------------------------------------------------------------
// Kernel 4: loss = (1 + beta) * sum / (N*D), beta = 0.25
// ---------------------------------------------------------------------------
__global__ void finalize_kernel(const float* __restrict__ accum,
                                float* __restrict__ out_loss)
{
    *out_loss = 1.25f * (*accum) / 8388608.0f;
}

// ---------------------------------------------------------------------------
extern "C" void kernel_launch(void* const* d_in, const int* in_sizes, int n_in,
                              void* d_out, int out_size, void* d_ws, size_t ws_size,
                              hipStream_t stream)
{
    const float* z   = (const float*)d_in[0];   // [65536,128]
    const float* emb = (const float*)d_in[1];   // [2048,128]
    float* out = (float*)d_out;                 // q(8388608) | idx-as-f32(65536) | loss(1)

    char*     ws       = (char*)d_ws;
    float*    enorm    = (float*)ws;                          // 8 KB
    float*    accum    = (float*)(ws + 8192);
    unsigned* cand_cnt = (unsigned*)(ws + 16384);             // 256 KB
    ushort*   cand     = (ushort*)(ws + 16384 + 262144);      // 4 MB
    ushort*   emb_bf   = (ushort*)(ws + 16384 + 262144 + 4194304);  // 512 KB

    prep_kernel   <<<NVEC / 256, 256, 0, stream>>>(emb, enorm, accum, cand_cnt, emb_bf);
    approx_kernel <<<256,        256, 0, stream>>>(z, emb_bf, enorm, cand_cnt, cand);
    rerank_kernel <<<NVEC / 64,  256, 0, stream>>>(z, emb, enorm, cand_cnt, cand,
                                                   out, out + 8388608, accum);
    finalize_kernel<<<1, 1, 0, stream>>>(accum, out + 8388608 + 65536);
}

// Round 8
// 275.701 us; speedup vs baseline: 9.4315x; 1.4354x over previous
//
#include <hip/hip_runtime.h>

#define NUM_EMB 2048
#define DIM     128
#define NVEC    65536            // 64*32*32
// MARGIN: needs >= 2*approx_err + fp32-bucket slop (~2.6e-4). 1e-3 = 4x
// headroom. Proven R7: absmax 0.0, rerank collapsed. DO NOT ENLARGE.
#define MARGIN  1.0e-3f
#define CAP     32               // candidates/row; overflow -> cooperative block scan (~dead at 1e-3)
#define CHUNK   256              // codes per LDS chunk in approx
#define NCHUNK  (NUM_EMB / CHUNK)
#define ES      136              // ushort stride/code in LDS: 272 B, 16B-aligned, 2-way banks (free)
#define ZS      132              // float stride/z-row in LDS

typedef float  f32x4 __attribute__((ext_vector_type(4)));
typedef short  s16x8 __attribute__((ext_vector_type(8)));

// RNE float -> bf16 (finite inputs)
__device__ __forceinline__ ushort f2bf(float f) {
    unsigned u = __float_as_uint(f);
    u = (u + 0x7fffu + ((u >> 16) & 1u)) >> 16;
    return (ushort)u;
}

// ---------------------------------------------------------------------------
// numpy pairwise_sum replica for n=128 fp32 applied to v*v (bit-exact vs np —
// verified R2-R7 absmax 0.0).  DO NOT REASSOCIATE.
// ---------------------------------------------------------------------------
__device__ __forceinline__ float np_pairwise_sumsq_128(const float* __restrict__ p)
{
    float r[8];
    #pragma unroll
    for (int j = 0; j < 8; ++j) { float v = p[j]; r[j] = __fmul_rn(v, v); }
    #pragma unroll
    for (int i = 8; i < 128; i += 8)
        #pragma unroll
        for (int j = 0; j < 8; ++j) { float v = p[i + j]; r[j] = __fadd_rn(r[j], __fmul_rn(v, v)); }
    float s01 = __fadd_rn(r[0], r[1]);
    float s23 = __fadd_rn(r[2], r[3]);
    float s45 = __fadd_rn(r[4], r[5]);
    float s67 = __fadd_rn(r[6], r[7]);
    return __fadd_rn(__fadd_rn(s01, s23), __fadd_rn(s45, s67));
}

// exact fp32-replica dot over one 32-k slab (ascending k, single accumulator)
__device__ __forceinline__ float dot_seg(const float4* __restrict__ zp,
                                         const float4* __restrict__ ep,
                                         int seg, float dot)
{
    float4 e[8], zz[8];
    #pragma unroll
    for (int i = 0; i < 8; ++i) { e[i] = ep[seg * 8 + i]; zz[i] = zp[seg * 8 + i]; }
    #pragma unroll
    for (int i = 0; i < 8; ++i) {
        dot = fmaf(zz[i].x, e[i].x, dot);
        dot = fmaf(zz[i].y, e[i].y, dot);
        dot = fmaf(zz[i].z, e[i].z, dot);
        dot = fmaf(zz[i].w, e[i].w, dot);
    }
    return dot;
}

// ---------------------------------------------------------------------------
// Kernel 1: enorm (np-exact) + emb->bf16 + zero accum/cand_cnt
// ---------------------------------------------------------------------------
__global__ __launch_bounds__(256)
void prep_kernel(const float* __restrict__ emb,
                 float* __restrict__ enorm,
                 float* __restrict__ accum,
                 unsigned* __restrict__ cand_cnt,
                 ushort* __restrict__ emb_bf)
{
    int g = blockIdx.x * 256 + threadIdx.x;
    cand_cnt[g] = 0u;
    if (g == 0) *accum = 0.0f;

    float4 v = ((const float4*)emb)[g];          // 65536 float4 == full emb
    ushort4 b;
    b.x = f2bf(v.x); b.y = f2bf(v.y); b.z = f2bf(v.z); b.w = f2bf(v.w);
    ((ushort4*)emb_bf)[g] = b;

    if (g < NUM_EMB)
        enorm[g] = np_pairwise_sumsq_128(emb + (size_t)g * DIM);
}

// ---------------------------------------------------------------------------
// Kernel 2: bf16-MFMA approx filter, single capture pass with running
// row-threshold (seed visit on chunk 0).
// R8 change: rows/wave 64 -> 32 (rt=2), grid 256 -> 512 => 2048 waves =
// 2 waves/SIMD, 2 blocks/CU (LDS 2x69KB=141KB <= 160KB).  R7 ran at exactly
// 1 wave/SIMD — latency-exposed (278 us vs ~30 us throughput floor).
// MFMA 16x16x32 bf16 layouts HW-verified (m89/m91).
// ---------------------------------------------------------------------------
__global__ __launch_bounds__(256, 2)
void approx_kernel(const float* __restrict__ z,
                   const ushort* __restrict__ emb_bf,
                   const float* __restrict__ enorm,
                   unsigned* __restrict__ cand_cnt,
                   ushort* __restrict__ cand)
{
    __shared__ __align__(16) ushort eS[CHUNK * ES];   // 69,632 B
    __shared__ float cS[CHUNK];

    const int tid  = threadIdx.x;
    const int w    = tid >> 6;
    const int lane = tid & 63;
    const int col  = lane & 15;           // m (A frag) / n (B frag) / D col
    const int quad = lane >> 4;           // k-group / D row-group
    const int rowbase = blockIdx.x * 128 + w * 32;    // 32 rows per wave

    // A-fragments: 2 row-tiles x 4 k-tiles, loaded once, fp32 -> bf16 RNE
    s16x8 afrag[2][4];
    #pragma unroll
    for (int rt = 0; rt < 2; ++rt) {
        const float* zr = z + (size_t)(rowbase + rt * 16 + col) * DIM;
        #pragma unroll
        for (int kt = 0; kt < 4; ++kt) {
            const float4* p = (const float4*)(zr + kt * 32 + quad * 8);
            float4 f0 = p[0], f1 = p[1];
            s16x8 a;
            a[0] = (short)f2bf(f0.x); a[1] = (short)f2bf(f0.y);
            a[2] = (short)f2bf(f0.z); a[3] = (short)f2bf(f0.w);
            a[4] = (short)f2bf(f1.x); a[5] = (short)f2bf(f1.y);
            a[6] = (short)f2bf(f1.z); a[7] = (short)f2bf(f1.w);
            afrag[rt][kt] = a;
        }
    }

    float minv[2][4], thr[2][4];
    #pragma unroll
    for (int rt = 0; rt < 2; ++rt)
        #pragma unroll
        for (int r = 0; r < 4; ++r) minv[rt][r] = 3.0e38f;

    // 9 chunk-visits: visit 0 = seed (chunk 0, min only), visits 1..8 = capture
    for (int vis = 0; vis < 9; ++vis) {
        const int c = (vis == 0) ? 0 : (vis - 1);
        __syncthreads();                 // previous chunk's readers done
        const uint4* src = (const uint4*)(emb_bf + (size_t)c * CHUNK * DIM);
        #pragma unroll
        for (int i = 0; i < 16; ++i) {
            int li   = i * 256 + tid;             // 0..4095
            int code = li >> 4, fc = li & 15;
            *(uint4*)&eS[code * ES + fc * 8] = src[li];
        }
        cS[tid] = enorm[c * CHUNK + tid];
        __syncthreads();

        #pragma unroll 4
        for (int t = 0; t < 16; ++t) {
            s16x8 bfrag[4];
            #pragma unroll
            for (int kt = 0; kt < 4; ++kt)
                bfrag[kt] = *(const s16x8*)&eS[(t * 16 + col) * ES + kt * 32 + quad * 8];

            f32x4 acc[2];
            #pragma unroll
            for (int rt = 0; rt < 2; ++rt) {
                f32x4 a = {0.0f, 0.0f, 0.0f, 0.0f};
                #pragma unroll
                for (int kt = 0; kt < 4; ++kt)
                    a = __builtin_amdgcn_mfma_f32_16x16x32_bf16(afrag[rt][kt], bfrag[kt], a, 0, 0, 0);
                acc[rt] = a;
            }

            float Cc     = cS[t * 16 + col];
            int   code_g = c * CHUNK + t * 16 + col;
            #pragma unroll
            for (int rt = 0; rt < 2; ++rt)
                #pragma unroll
                for (int r = 0; r < 4; ++r) {
                    float g = fmaf(-2.0f, acc[rt][r], Cc);
                    minv[rt][r] = fminf(minv[rt][r], g);
                    if (vis > 0 && g <= thr[rt][r]) {
                        int row_g = rowbase + rt * 16 + quad * 4 + r;
                        unsigned pos = atomicAdd(&cand_cnt[row_g], 1u);
                        if (pos < CAP) cand[(size_t)row_g * CAP + pos] = (ushort)code_g;
                    }
                }
        }

        // refresh row-wide threshold: butterfly min across the 16 cols
        #pragma unroll
        for (int rt = 0; rt < 2; ++rt)
            #pragma unroll
            for (int r = 0; r < 4; ++r) {
                float v = minv[rt][r];
                v = fminf(v, __shfl_xor(v, 1, 64));
                v = fminf(v, __shfl_xor(v, 2, 64));
                v = fminf(v, __shfl_xor(v, 4, 64));
                v = fminf(v, __shfl_xor(v, 8, 64));
                minv[rt][r] = v;
                thr[rt][r]  = v + MARGIN;
            }
    }
}

// ---------------------------------------------------------------------------
// Kernel 3: exact fp32-replica re-rank + cooperative overflow scan + fused
// gather/loss epilogue (unchanged from R6/R7 — verified).
// ---------------------------------------------------------------------------
__global__ __launch_bounds__(256)
void rerank_kernel(const float* __restrict__ z,
                   const float* __restrict__ emb,
                   const float* __restrict__ enorm,
                   const unsigned* __restrict__ cand_cnt,
                   const ushort* __restrict__ cand,
                   float* __restrict__ out_q,
                   float* __restrict__ out_idx_f,
                   float* __restrict__ accum)
{
    __shared__ float zs[64 * ZS];        // 33,792 B
    __shared__ float As[64];
    __shared__ int   bidx[64];
    __shared__ int   ovf_list[64];
    __shared__ int   ovf_n;
    __shared__ float rv[4];
    __shared__ int   rvi[4];
    __shared__ float wsum[4];

    const int tid = threadIdx.x;
    const int m0  = blockIdx.x * 64;
    if (tid == 0) ovf_n = 0;

    // stage z tile, coalesced
    #pragma unroll
    for (int i = 0; i < 8; ++i) {
        int li = tid + i * 256;          // 0..2047
        int m  = li >> 5, dc = li & 31;
        float4 v = ((const float4*)(z + (size_t)(m0 + m) * DIM))[dc];
        *(float4*)&zs[m * ZS + dc * 4] = v;
    }
    __syncthreads();
    if (tid < 64) As[tid] = np_pairwise_sumsq_128(&zs[tid * ZS]);
    __syncthreads();

    const int row_l = tid >> 2;          // 4 contiguous lanes per row
    const int sub   = tid & 3;
    const int row_g = m0 + row_l;
    const unsigned cnt = cand_cnt[row_g];
    const float A = As[row_l];
    const float4* zp = (const float4*)&zs[row_l * ZS];

    float bv = 3.0e38f;
    int   bi = 0x7fffffff;

    if (cnt <= CAP) {                    // candidate path (split over 4 lanes)
        for (unsigned ci = sub; ci < cnt; ci += 4) {
            int j = (int)cand[(size_t)row_g * CAP + ci];
            const float4* ep = (const float4*)(emb + (size_t)j * DIM);
            float dot = 0.0f;
            #pragma unroll
            for (int seg = 0; seg < 4; ++seg) dot = dot_seg(zp, ep, seg, dot);
            float t1 = fmaf(-2.0f, dot, A);
            float s  = __fadd_rn(t1, enorm[j]);
            if (s < bv || (s == bv && j < bi)) { bv = s; bi = j; }
        }
    }
    // (val,idx) min-reduce across the 4 lanes of this row
    #pragma unroll
    for (int off = 1; off <= 2; off <<= 1) {
        float v  = __shfl_xor(bv, off, 64);
        int   ix = __shfl_xor(bi, off, 64);
        if (v < bv || (v == bv && ix < bi)) { bv = v; bi = ix; }
    }
    if (sub == 0) {
        if (cnt <= CAP) bidx[row_l] = bi;
        else { int p = atomicAdd(&ovf_n, 1); ovf_list[p] = row_l; }
    }
    __syncthreads();

    // cooperative exact scan of overflow rows: 256 thr x 8 ascending codes
    const int n_ovf = ovf_n;
    for (int o = 0; o < n_ovf; ++o) {
        const int rl = ovf_list[o];
        const float Ar = As[rl];
        const float4* zp2 = (const float4*)&zs[rl * ZS];
        float bv2 = 3.0e38f;
        int   bi2 = 0x7fffffff;
        for (int jj = 0; jj < 8; ++jj) {
            int j = tid * 8 + jj;        // ascending within thread -> strict <
            const float4* ep = (const float4*)(emb + (size_t)j * DIM);
            float dot = 0.0f;
            #pragma unroll
            for (int seg = 0; seg < 4; ++seg) dot = dot_seg(zp2, ep, seg, dot);
            float t1 = fmaf(-2.0f, dot, Ar);
            float s  = __fadd_rn(t1, enorm[j]);
            if (s < bv2) { bv2 = s; bi2 = j; }
        }
        #pragma unroll
        for (int off = 1; off < 64; off <<= 1) {
            float v  = __shfl_xor(bv2, off, 64);
            int   ix = __shfl_xor(bi2, off, 64);
            if (v < bv2 || (v == bv2 && ix < bi2)) { bv2 = v; bi2 = ix; }
        }
        if ((tid & 63) == 0) { rv[tid >> 6] = bv2; rvi[tid >> 6] = bi2; }
        __syncthreads();
        if (tid == 0) {
            float fv = rv[0]; int fi = rvi[0];
            #pragma unroll
            for (int ww = 1; ww < 4; ++ww) {
                if (rv[ww] < fv || (rv[ww] == fv && rvi[ww] < fi)) { fv = rv[ww]; fi = rvi[ww]; }
            }
            bidx[rl] = fi;
        }
        __syncthreads();
    }

    if (tid < 64) out_idx_f[m0 + tid] = (float)bidx[tid];

    // fused gather + straight-through + loss partial (zs still intact)
    float part = 0.0f;
    #pragma unroll
    for (int i = 0; i < 8; ++i) {
        int li = tid + i * 256;
        int m  = li >> 5, dc = li & 31;
        int j  = bidx[m];
        float4 q  = ((const float4*)(emb + (size_t)j * DIM))[dc];
        float4 zv = *(const float4*)&zs[m * ZS + dc * 4];
        float4 o;
        o.x = __fadd_rn(zv.x, __fsub_rn(q.x, zv.x));
        o.y = __fadd_rn(zv.y, __fsub_rn(q.y, zv.y));
        o.z = __fadd_rn(zv.z, __fsub_rn(q.z, zv.z));
        o.w = __fadd_rn(zv.w, __fsub_rn(q.w, zv.w));
        ((float4*)out_q)[(size_t)(m0 + m) * 32 + dc] = o;
        float dx = q.x - zv.x, dy = q.y - zv.y, dz = q.z - zv.z, dw = q.w - zv.w;
        part += dx * dx + dy * dy + dz * dz + dw * dw;
    }
    #pragma unroll
    for (int off = 32; off > 0; off >>= 1)
        part += __shfl_down(part, off, 64);
    if ((tid & 63) == 0) wsum[tid >> 6] = part;
    __syncthreads();
    if (tid == 0) atomicAdd(accum, wsum[0] + wsum[1] + wsum[2] + wsum[3]);
}

// ---------------------------------------------------------------------------
// Kernel 4: loss = (1 + beta) * sum / (N*D), beta = 0.25
// ---------------------------------------------------------------------------
__global__ void finalize_kernel(const float* __restrict__ accum,
                                float* __restrict__ out_loss)
{
    *out_loss = 1.25f * (*accum) / 8388608.0f;
}

// ---------------------------------------------------------------------------
extern "C" void kernel_launch(void* const* d_in, const int* in_sizes, int n_in,
                              void* d_out, int out_size, void* d_ws, size_t ws_size,
                              hipStream_t stream)
{
    const float* z   = (const float*)d_in[0];   // [65536,128]
    const float* emb = (const float*)d_in[1];   // [2048,128]
    float* out = (float*)d_out;                 // q(8388608) | idx-as-f32(65536) | loss(1)

    char*     ws       = (char*)d_ws;
    float*    enorm    = (float*)ws;                          // 8 KB
    float*    accum    = (float*)(ws + 8192);
    unsigned* cand_cnt = (unsigned*)(ws + 16384);             // 256 KB
    ushort*   cand     = (ushort*)(ws + 16384 + 262144);      // 4 MB
    ushort*   emb_bf   = (ushort*)(ws + 16384 + 262144 + 4194304);  // 512 KB

    prep_kernel   <<<NVEC / 256, 256, 0, stream>>>(emb, enorm, accum, cand_cnt, emb_bf);
    approx_kernel <<<512,        256, 0, stream>>>(z, emb_bf, enorm, cand_cnt, cand);
    rerank_kernel <<<NVEC / 64,  256, 0, stream>>>(z, emb, enorm, cand_cnt, cand,
                                                   out, out + 8388608, accum);
    finalize_kernel<<<1, 1, 0, stream>>>(accum, out + 8388608 + 65536);
}

// Round 9
// 225.713 us; speedup vs baseline: 11.5202x; 1.2215x over previous
//
#include <hip/hip_runtime.h>

#define NUM_EMB 2048
#define DIM     128
#define NVEC    65536            // 64*32*32
// MARGIN: needs >= 2*approx_err + fp32-bucket slop (~2.6e-4). 1e-3 = 4x
// headroom. Proven R7/R8: absmax 0.0. DO NOT ENLARGE (R6's 4e-3 -> 1.9 ms rerank).
#define MARGIN  1.0e-3f
#define CAP     32               // candidates/row; overflow -> cooperative block scan (~dead at 1e-3)
#define CHUNK   256              // codes per LDS chunk in approx
#define NCHUNK  (NUM_EMB / CHUNK)
#define ES      136              // ushort stride/code in LDS: 272 B, 16B-aligned, 2-way banks (free)
#define ZS      132              // float stride/z-row in LDS

typedef float  f32x4 __attribute__((ext_vector_type(4)));
typedef short  s16x8 __attribute__((ext_vector_type(8)));

// RNE float -> bf16 (finite inputs)
__device__ __forceinline__ ushort f2bf(float f) {
    unsigned u = __float_as_uint(f);
    u = (u + 0x7fffu + ((u >> 16) & 1u)) >> 16;
    return (ushort)u;
}

// ---------------------------------------------------------------------------
// numpy pairwise_sum replica for n=128 fp32 applied to v*v (bit-exact vs np —
// verified R2-R8 absmax 0.0).  DO NOT REASSOCIATE.
// ---------------------------------------------------------------------------
__device__ __forceinline__ float np_pairwise_sumsq_128(const float* __restrict__ p)
{
    float r[8];
    #pragma unroll
    for (int j = 0; j < 8; ++j) { float v = p[j]; r[j] = __fmul_rn(v, v); }
    #pragma unroll
    for (int i = 8; i < 128; i += 8)
        #pragma unroll
        for (int j = 0; j < 8; ++j) { float v = p[i + j]; r[j] = __fadd_rn(r[j], __fmul_rn(v, v)); }
    float s01 = __fadd_rn(r[0], r[1]);
    float s23 = __fadd_rn(r[2], r[3]);
    float s45 = __fadd_rn(r[4], r[5]);
    float s67 = __fadd_rn(r[6], r[7]);
    return __fadd_rn(__fadd_rn(s01, s23), __fadd_rn(s45, s67));
}

// exact fp32-replica dot over one 32-k slab (ascending k, single accumulator)
__device__ __forceinline__ float dot_seg(const float4* __restrict__ zp,
                                         const float4* __restrict__ ep,
                                         int seg, float dot)
{
    float4 e[8], zz[8];
    #pragma unroll
    for (int i = 0; i < 8; ++i) { e[i] = ep[seg * 8 + i]; zz[i] = zp[seg * 8 + i]; }
    #pragma unroll
    for (int i = 0; i < 8; ++i) {
        dot = fmaf(zz[i].x, e[i].x, dot);
        dot = fmaf(zz[i].y, e[i].y, dot);
        dot = fmaf(zz[i].z, e[i].z, dot);
        dot = fmaf(zz[i].w, e[i].w, dot);
    }
    return dot;
}

// ---------------------------------------------------------------------------
// Kernel 1: enorm (np-exact) + emb->bf16 + zero accum/cand_cnt
// ---------------------------------------------------------------------------
__global__ __launch_bounds__(256)
void prep_kernel(const float* __restrict__ emb,
                 float* __restrict__ enorm,
                 float* __restrict__ accum,
                 unsigned* __restrict__ cand_cnt,
                 ushort* __restrict__ emb_bf)
{
    int g = blockIdx.x * 256 + threadIdx.x;
    cand_cnt[g] = 0u;
    if (g == 0) *accum = 0.0f;

    float4 v = ((const float4*)emb)[g];          // 65536 float4 == full emb
    ushort4 b;
    b.x = f2bf(v.x); b.y = f2bf(v.y); b.z = f2bf(v.z); b.w = f2bf(v.w);
    ((ushort4*)emb_bf)[g] = b;

    if (g < NUM_EMB)
        enorm[g] = np_pairwise_sumsq_128(emb + (size_t)g * DIM);
}

// ---------------------------------------------------------------------------
// Kernel 2: bf16-MFMA approx filter, single capture pass with running
// row-threshold (seed visit on chunk 0).
// R9: 1024-thread blocks (16 waves), 16 rows/wave (rt=1), grid=256 =
// 1 block/CU => 4096 waves = 4 waves/SIMD — the occupancy CEILING of this
// decomposition (wave granularity = one 16-row MFMA M-tile).  Evidence:
// R7->R8 waves/SIMD 1->2 gave time /1.76 while LDS traffic doubled =>
// per-wave-latency-bound, throughput scales with resident waves.
// MFMA 16x16x32 bf16 layouts HW-verified (m89/m91).
// ---------------------------------------------------------------------------
__global__ __launch_bounds__(1024, 1)
void approx_kernel(const float* __restrict__ z,
                   const ushort* __restrict__ emb_bf,
                   const float* __restrict__ enorm,
                   unsigned* __restrict__ cand_cnt,
                   ushort* __restrict__ cand)
{
    __shared__ __align__(16) ushort eS[CHUNK * ES];   // 69,632 B
    __shared__ float cS[CHUNK];

    const int tid  = threadIdx.x;         // 0..1023
    const int w    = tid >> 6;            // wave 0..15
    const int lane = tid & 63;
    const int col  = lane & 15;           // m (A frag) / n (B frag) / D col
    const int quad = lane >> 4;           // k-group / D row-group
    const int rowbase = blockIdx.x * 256 + w * 16;    // 16 rows per wave

    // A-fragments: 4 k-tiles for this wave's 16 rows, loaded once, fp32->bf16
    s16x8 afrag[4];
    {
        const float* zr = z + (size_t)(rowbase + col) * DIM;
        #pragma unroll
        for (int kt = 0; kt < 4; ++kt) {
            const float4* p = (const float4*)(zr + kt * 32 + quad * 8);
            float4 f0 = p[0], f1 = p[1];
            s16x8 a;
            a[0] = (short)f2bf(f0.x); a[1] = (short)f2bf(f0.y);
            a[2] = (short)f2bf(f0.z); a[3] = (short)f2bf(f0.w);
            a[4] = (short)f2bf(f1.x); a[5] = (short)f2bf(f1.y);
            a[6] = (short)f2bf(f1.z); a[7] = (short)f2bf(f1.w);
            afrag[kt] = a;
        }
    }

    float minv[4], thr[4];
    #pragma unroll
    for (int r = 0; r < 4; ++r) minv[r] = 3.0e38f;

    // 9 chunk-visits: visit 0 = seed (chunk 0, min only), visits 1..8 = capture
    for (int vis = 0; vis < 9; ++vis) {
        const int c = (vis == 0) ? 0 : (vis - 1);
        __syncthreads();                 // previous chunk's readers done
        const uint4* src = (const uint4*)(emb_bf + (size_t)c * CHUNK * DIM);
        #pragma unroll
        for (int i = 0; i < 4; ++i) {
            int li   = i * 1024 + tid;            // 0..4095
            int code = li >> 4, fc = li & 15;
            *(uint4*)&eS[code * ES + fc * 8] = src[li];
        }
        if (tid < CHUNK) cS[tid] = enorm[c * CHUNK + tid];
        __syncthreads();

        #pragma unroll 4
        for (int t = 0; t < 16; ++t) {
            s16x8 bfrag[4];
            #pragma unroll
            for (int kt = 0; kt < 4; ++kt)
                bfrag[kt] = *(const s16x8*)&eS[(t * 16 + col) * ES + kt * 32 + quad * 8];

            f32x4 a = {0.0f, 0.0f, 0.0f, 0.0f};
            #pragma unroll
            for (int kt = 0; kt < 4; ++kt)
                a = __builtin_amdgcn_mfma_f32_16x16x32_bf16(afrag[kt], bfrag[kt], a, 0, 0, 0);

            float Cc     = cS[t * 16 + col];
            int   code_g = c * CHUNK + t * 16 + col;
            #pragma unroll
            for (int r = 0; r < 4; ++r) {
                float g = fmaf(-2.0f, a[r], Cc);
                minv[r] = fminf(minv[r], g);
                if (vis > 0 && g <= thr[r]) {
                    int row_g = rowbase + quad * 4 + r;
                    unsigned pos = atomicAdd(&cand_cnt[row_g], 1u);
                    if (pos < CAP) cand[(size_t)row_g * CAP + pos] = (ushort)code_g;
                }
            }
        }

        // refresh row-wide threshold: butterfly min across the 16 cols
        #pragma unroll
        for (int r = 0; r < 4; ++r) {
            float v = minv[r];
            v = fminf(v, __shfl_xor(v, 1, 64));
            v = fminf(v, __shfl_xor(v, 2, 64));
            v = fminf(v, __shfl_xor(v, 4, 64));
            v = fminf(v, __shfl_xor(v, 8, 64));
            minv[r] = v;
            thr[r]  = v + MARGIN;
        }
    }
}

// ---------------------------------------------------------------------------
// Kernel 3: exact fp32-replica re-rank + cooperative overflow scan + fused
// gather/loss epilogue (unchanged from R6/R7/R8 — verified).
// ---------------------------------------------------------------------------
__global__ __launch_bounds__(256)
void rerank_kernel(const float* __restrict__ z,
                   const float* __restrict__ emb,
                   const float* __restrict__ enorm,
                   const unsigned* __restrict__ cand_cnt,
                   const ushort* __restrict__ cand,
                   float* __restrict__ out_q,
                   float* __restrict__ out_idx_f,
                   float* __restrict__ accum)
{
    __shared__ float zs[64 * ZS];        // 33,792 B
    __shared__ float As[64];
    __shared__ int   bidx[64];
    __shared__ int   ovf_list[64];
    __shared__ int   ovf_n;
    __shared__ float rv[4];
    __shared__ int   rvi[4];
    __shared__ float wsum[4];

    const int tid = threadIdx.x;
    const int m0  = blockIdx.x * 64;
    if (tid == 0) ovf_n = 0;

    // stage z tile, coalesced
    #pragma unroll
    for (int i = 0; i < 8; ++i) {
        int li = tid + i * 256;          // 0..2047
        int m  = li >> 5, dc = li & 31;
        float4 v = ((const float4*)(z + (size_t)(m0 + m) * DIM))[dc];
        *(float4*)&zs[m * ZS + dc * 4] = v;
    }
    __syncthreads();
    if (tid < 64) As[tid] = np_pairwise_sumsq_128(&zs[tid * ZS]);
    __syncthreads();

    const int row_l = tid >> 2;          // 4 contiguous lanes per row
    const int sub   = tid & 3;
    const int row_g = m0 + row_l;
    const unsigned cnt = cand_cnt[row_g];
    const float A = As[row_l];
    const float4* zp = (const float4*)&zs[row_l * ZS];

    float bv = 3.0e38f;
    int   bi = 0x7fffffff;

    if (cnt <= CAP) {                    // candidate path (split over 4 lanes)
        for (unsigned ci = sub; ci < cnt; ci += 4) {
            int j = (int)cand[(size_t)row_g * CAP + ci];
            const float4* ep = (const float4*)(emb + (size_t)j * DIM);
            float dot = 0.0f;
            #pragma unroll
            for (int seg = 0; seg < 4; ++seg) dot = dot_seg(zp, ep, seg, dot);
            float t1 = fmaf(-2.0f, dot, A);
            float s  = __fadd_rn(t1, enorm[j]);
            if (s < bv || (s == bv && j < bi)) { bv = s; bi = j; }
        }
    }
    // (val,idx) min-reduce across the 4 lanes of this row
    #pragma unroll
    for (int off = 1; off <= 2; off <<= 1) {
        float v  = __shfl_xor(bv, off, 64);
        int   ix = __shfl_xor(bi, off, 64);
        if (v < bv || (v == bv && ix < bi)) { bv = v; bi = ix; }
    }
    if (sub == 0) {
        if (cnt <= CAP) bidx[row_l] = bi;
        else { int p = atomicAdd(&ovf_n, 1); ovf_list[p] = row_l; }
    }
    __syncthreads();

    // cooperative exact scan of overflow rows: 256 thr x 8 ascending codes
    const int n_ovf = ovf_n;
    for (int o = 0; o < n_ovf; ++o) {
        const int rl = ovf_list[o];
        const float Ar = As[rl];
        const float4* zp2 = (const float4*)&zs[rl * ZS];
        float bv2 = 3.0e38f;
        int   bi2 = 0x7fffffff;
        for (int jj = 0; jj < 8; ++jj) {
            int j = tid * 8 + jj;        // ascending within thread -> strict <
            const float4* ep = (const float4*)(emb + (size_t)j * DIM);
            float dot = 0.0f;
            #pragma unroll
            for (int seg = 0; seg < 4; ++seg) dot = dot_seg(zp2, ep, seg, dot);
            float t1 = fmaf(-2.0f, dot, Ar);
            float s  = __fadd_rn(t1, enorm[j]);
            if (s < bv2) { bv2 = s; bi2 = j; }
        }
        #pragma unroll
        for (int off = 1; off < 64; off <<= 1) {
            float v  = __shfl_xor(bv2, off, 64);
            int   ix = __shfl_xor(bi2, off, 64);
            if (v < bv2 || (v == bv2 && ix < bi2)) { bv2 = v; bi2 = ix; }
        }
        if ((tid & 63) == 0) { rv[tid >> 6] = bv2; rvi[tid >> 6] = bi2; }
        __syncthreads();
        if (tid == 0) {
            float fv = rv[0]; int fi = rvi[0];
            #pragma unroll
            for (int ww = 1; ww < 4; ++ww) {
                if (rv[ww] < fv || (rv[ww] == fv && rvi[ww] < fi)) { fv = rv[ww]; fi = rvi[ww]; }
            }
            bidx[rl] = fi;
        }
        __syncthreads();
    }

    if (tid < 64) out_idx_f[m0 + tid] = (float)bidx[tid];

    // fused gather + straight-through + loss partial (zs still intact)
    float part = 0.0f;
    #pragma unroll
    for (int i = 0; i < 8; ++i) {
        int li = tid + i * 256;
        int m  = li >> 5, dc = li & 31;
        int j  = bidx[m];
        float4 q  = ((const float4*)(emb + (size_t)j * DIM))[dc];
        float4 zv = *(const float4*)&zs[m * ZS + dc * 4];
        float4 o;
        o.x = __fadd_rn(zv.x, __fsub_rn(q.x, zv.x));
        o.y = __fadd_rn(zv.y, __fsub_rn(q.y, zv.y));
        o.z = __fadd_rn(zv.z, __fsub_rn(q.z, zv.z));
        o.w = __fadd_rn(zv.w, __fsub_rn(q.w, zv.w));
        ((float4*)out_q)[(size_t)(m0 + m) * 32 + dc] = o;
        float dx = q.x - zv.x, dy = q.y - zv.y, dz = q.z - zv.z, dw = q.w - zv.w;
        part += dx * dx + dy * dy + dz * dz + dw * dw;
    }
    #pragma unroll
    for (int off = 32; off > 0; off >>= 1)
        part += __shfl_down(part, off, 64);
    if ((tid & 63) == 0) wsum[tid >> 6] = part;
    __syncthreads();
    if (tid == 0) atomicAdd(accum, wsum[0] + wsum[1] + wsum[2] + wsum[3]);
}

// ---------------------------------------------------------------------------
// Kernel 4: loss = (1 + beta) * sum / (N*D), beta = 0.25
// ---------------------------------------------------------------------------
__global__ void finalize_kernel(const float* __restrict__ accum,
                                float* __restrict__ out_loss)
{
    *out_loss = 1.25f * (*accum) / 8388608.0f;
}

// ---------------------------------------------------------------------------
extern "C" void kernel_launch(void* const* d_in, const int* in_sizes, int n_in,
                              void* d_out, int out_size, void* d_ws, size_t ws_size,
                              hipStream_t stream)
{
    const float* z   = (const float*)d_in[0];   // [65536,128]
    const float* emb = (const float*)d_in[1];   // [2048,128]
    float* out = (float*)d_out;                 // q(8388608) | idx-as-f32(65536) | loss(1)

    char*     ws       = (char*)d_ws;
    float*    enorm    = (float*)ws;                          // 8 KB
    float*    accum    = (float*)(ws + 8192);
    unsigned* cand_cnt = (unsigned*)(ws + 16384);             // 256 KB
    ushort*   cand     = (ushort*)(ws + 16384 + 262144);      // 4 MB
    ushort*   emb_bf   = (ushort*)(ws + 16384 + 262144 + 4194304);  // 512 KB

    prep_kernel   <<<NVEC / 256, 256,  0, stream>>>(emb, enorm, accum, cand_cnt, emb_bf);
    approx_kernel <<<256,        1024, 0, stream>>>(z, emb_bf, enorm, cand_cnt, cand);
    rerank_kernel <<<NVEC / 64,  256,  0, stream>>>(z, emb, enorm, cand_cnt, cand,
                                                    out, out + 8388608, accum);
    finalize_kernel<<<1, 1, 0, stream>>>(accum, out + 8388608 + 65536);
}